// Round 1
// baseline (1773.782 us; speedup 1.0000x reference)
//
#include <hip/hip_runtime.h>

#define B_SZ 4
#define CIN 1024
#define DHI 2048
#define TT 8192
#define KEEP 512
#define OUT_ELEMS (B_SZ*CIN*TT)            // 33554432
#define SPARSE_PER_B (DHI*TT)              // 16777216
#define THRESH 3.0f

#define BM 128
#define BN 128
#define BK 16

// counters layout: [0..3]=cand count per batch, [4..7]=sel count, [8..11]=tie count
__global__ __launch_bounds__(256) void fill_kernel(const float* __restrict__ bcon,
                                                   float* __restrict__ out,
                                                   unsigned* __restrict__ counters) {
    const int OUT4 = OUT_ELEMS / 4;
    const int TOT4 = (OUT_ELEMS + B_SZ * SPARSE_PER_B) / 4;
    float4* o4 = (float4*)out;
    for (int i = blockIdx.x * blockDim.x + threadIdx.x; i < TOT4;
         i += gridDim.x * blockDim.x) {
        float4 v;
        if (i < OUT4) {
            float bc = bcon[(i >> 11) & (CIN - 1)];
            v = make_float4(bc, bc, bc, bc);
        } else {
            v = make_float4(0.f, 0.f, 0.f, 0.f);
        }
        o4[i] = v;
    }
    if (blockIdx.x == 0 && threadIdx.x < 16) counters[threadIdx.x] = 0;
}

__global__ __launch_bounds__(256) void gemm1_cand(const float* __restrict__ x,
                                                  const float* __restrict__ Wexp,
                                                  const float* __restrict__ bexp,
                                                  float* __restrict__ cand_val,
                                                  unsigned* __restrict__ cand_idx,
                                                  unsigned* __restrict__ counters,
                                                  int cap) {
    __shared__ float As[BK][BM + 4];
    __shared__ float Bs[BK][BN];
    __shared__ unsigned s_cnt, s_base;
    __shared__ float s_cv[512];
    __shared__ unsigned s_ci[512];

    const int tid = threadIdx.x;
    const int tx = tid & 15;
    const int ty = tid >> 4;
    const int b  = blockIdx.z;
    const int bm = blockIdx.y * BM;
    const int bn = blockIdx.x * BN;
    const float* xb = x + (size_t)b * CIN * TT;

    float acc[8][8];
#pragma unroll
    for (int i = 0; i < 8; ++i)
#pragma unroll
        for (int j = 0; j < 8; ++j) acc[i][j] = 0.f;

    for (int k0 = 0; k0 < CIN; k0 += BK) {
        // A tile: 128 rows x 16 k -> transposed into As[k][m]
#pragma unroll
        for (int i = 0; i < 2; ++i) {
            int f = tid + i * 256;           // 0..511
            int m = f >> 2, kq = f & 3;
            float4 a = *(const float4*)(&Wexp[(size_t)(bm + m) * CIN + k0 + kq * 4]);
            As[kq * 4 + 0][m] = a.x;
            As[kq * 4 + 1][m] = a.y;
            As[kq * 4 + 2][m] = a.z;
            As[kq * 4 + 3][m] = a.w;
        }
        // B tile: 16 rows x 128 t, linear
#pragma unroll
        for (int i = 0; i < 2; ++i) {
            int f = tid + i * 256;           // 0..511
            int kk = f >> 5, cq = f & 31;
            *(float4*)(&Bs[kk][cq * 4]) =
                *(const float4*)(&xb[(size_t)(k0 + kk) * TT + bn + cq * 4]);
        }
        __syncthreads();
#pragma unroll
        for (int k = 0; k < BK; ++k) {
            float4 a0 = *(const float4*)&As[k][ty * 4];
            float4 a1 = *(const float4*)&As[k][64 + ty * 4];
            float4 b0 = *(const float4*)&Bs[k][tx * 4];
            float4 b1 = *(const float4*)&Bs[k][64 + tx * 4];
            float av[8] = {a0.x, a0.y, a0.z, a0.w, a1.x, a1.y, a1.z, a1.w};
            float bv[8] = {b0.x, b0.y, b0.z, b0.w, b1.x, b1.y, b1.z, b1.w};
#pragma unroll
            for (int i = 0; i < 8; ++i)
#pragma unroll
                for (int j = 0; j < 8; ++j) acc[i][j] += av[i] * bv[j];
        }
        __syncthreads();
    }

    // Epilogue: add bias, collect threshold candidates into LDS, flush once.
    if (tid == 0) s_cnt = 0;
    __syncthreads();
#pragma unroll
    for (int i = 0; i < 8; ++i) {
        int d = bm + ((i < 4) ? (ty * 4 + i) : (64 + ty * 4 + (i - 4)));
        float bias = bexp[d];
#pragma unroll
        for (int j = 0; j < 8; ++j) {
            int t = bn + ((j < 4) ? (tx * 4 + j) : (64 + tx * 4 + (j - 4)));
            float val = acc[i][j] + bias;
            if (val > THRESH) {
                unsigned p = atomicAdd(&s_cnt, 1u);
                if (p < 512u) {
                    s_cv[p] = val;
                    s_ci[p] = (unsigned)(d * TT + t);
                }
            }
        }
    }
    __syncthreads();
    unsigned n = s_cnt < 512u ? s_cnt : 512u;
    if (tid == 0) s_base = atomicAdd(&counters[b], n);
    __syncthreads();
    unsigned base = s_base;
    for (unsigned i = tid; i < n; i += 256u) {
        unsigned pos = base + i;
        if (pos < (unsigned)cap) {
            cand_val[(size_t)b * cap + pos] = s_cv[i];
            cand_idx[(size_t)b * cap + pos] = s_ci[i];
        }
    }
}

// One block per batch: radix-select the 512th-largest value among candidates
// (all > 3.0 > 0 so float bits are monotone as uint), then emit exactly 512
// selected entries + scatter them into the sparse output region.
__global__ __launch_bounds__(256) void select_topk(const float* __restrict__ cand_val,
                                                   const unsigned* __restrict__ cand_idx,
                                                   unsigned* __restrict__ counters,
                                                   float* __restrict__ sel_val,
                                                   unsigned* __restrict__ sel_idx,
                                                   float* __restrict__ d_out,
                                                   int cap) {
    const int b = blockIdx.x;
    const int tid = threadIdx.x;
    const float* cv = cand_val + (size_t)b * cap;
    const unsigned* ci = cand_idx + (size_t)b * cap;
    unsigned nc = counters[b];
    int n = (int)(nc < (unsigned)cap ? nc : (unsigned)cap);

    __shared__ unsigned hist[256];
    __shared__ unsigned s_sel, s_rem;

    unsigned prefix = 0;
    int remaining = KEEP;
    for (int pass = 0; pass < 4; ++pass) {
        int shift = 24 - pass * 8;
        for (int i = tid; i < 256; i += 256) hist[i] = 0;
        __syncthreads();
        for (int i = tid; i < n; i += 256) {
            unsigned u = __float_as_uint(cv[i]);
            unsigned hi = (pass == 0) ? 0u : (u >> (shift + 8));
            if (hi == prefix) atomicAdd(&hist[(u >> shift) & 255u], 1u);
        }
        __syncthreads();
        if (tid == 0) {
            int rem = remaining;
            unsigned selb = 0;
            for (int byte = 255; byte >= 0; --byte) {
                int c = (int)hist[byte];
                if (c >= rem) { selb = (unsigned)byte; break; }
                rem -= c;
            }
            s_sel = selb;
            s_rem = (unsigned)rem;
        }
        __syncthreads();
        prefix = (prefix << 8) | s_sel;
        remaining = (int)s_rem;
        __syncthreads();
    }
    const unsigned kth = prefix;

    float* sparse = d_out + (size_t)OUT_ELEMS + (size_t)b * SPARSE_PER_B;
    for (int i = tid; i < n; i += 256) {
        float v = cv[i];
        unsigned u = __float_as_uint(v);
        bool take = false;
        if (u > kth) {
            take = true;
        } else if (u == kth) {
            unsigned t = atomicAdd(&counters[8 + b], 1u);
            take = (t < (unsigned)remaining);
        }
        if (take) {
            unsigned p = atomicAdd(&counters[4 + b], 1u);
            unsigned idx = ci[i];
            sel_val[b * KEEP + p] = v;
            sel_idx[b * KEEP + p] = idx;
            sparse[idx] = v;
        }
    }
}

// out[b,:,t] += v * W_con[:,d] for each of the 512 selected entries per batch.
__global__ __launch_bounds__(256) void scatter_out(const float* __restrict__ sel_val,
                                                   const unsigned* __restrict__ sel_idx,
                                                   const float* __restrict__ Wcon,
                                                   float* __restrict__ out) {
    const int b = blockIdx.x >> 9;
    const int j = blockIdx.x & 511;
    const float v = sel_val[b * KEEP + j];
    const unsigned idx = sel_idx[b * KEEP + j];
    const int d = (int)(idx >> 13);          // T = 8192 = 2^13
    const int t = (int)(idx & 8191u);
    const int tid = threadIdx.x;
#pragma unroll
    for (int i = 0; i < 4; ++i) {
        int c = tid + i * 256;
        float w = Wcon[(size_t)c * DHI + d];
        atomicAdd(&out[(((size_t)(b * CIN + c)) << 13) + t], v * w);
    }
}

extern "C" void kernel_launch(void* const* d_in, const int* in_sizes, int n_in,
                              void* d_out, int out_size, void* d_ws, size_t ws_size,
                              hipStream_t stream) {
    const float* x    = (const float*)d_in[0];
    const float* Wexp = (const float*)d_in[1];
    const float* bexp = (const float*)d_in[2];
    const float* Wcon = (const float*)d_in[3];
    const float* bcon = (const float*)d_in[4];
    float* out = (float*)d_out;

    // Workspace layout
    unsigned* counters = (unsigned*)d_ws;                                  // 64 B
    float*    sel_val  = (float*)((char*)d_ws + 64);                       // B*512 f32
    unsigned* sel_idx  = (unsigned*)((char*)d_ws + 64 + B_SZ * KEEP * 4);  // B*512 u32
    char* cand_base = (char*)d_ws + 64 + (size_t)B_SZ * KEEP * 8;
    size_t remain = ws_size - (64 + (size_t)B_SZ * KEEP * 8);
    size_t cap_sz = remain / ((size_t)B_SZ * 8);
    int cap = (int)(cap_sz < (size_t)65536 ? cap_sz : (size_t)65536);
    float*    cand_val = (float*)cand_base;
    unsigned* cand_idx = (unsigned*)(cand_base + (size_t)B_SZ * cap * 4);

    fill_kernel<<<4096, 256, 0, stream>>>(bcon, out, counters);

    dim3 g(TT / BN, DHI / BM, B_SZ);
    gemm1_cand<<<g, 256, 0, stream>>>(x, Wexp, bexp, cand_val, cand_idx, counters, cap);

    select_topk<<<B_SZ, 256, 0, stream>>>(cand_val, cand_idx, counters,
                                          sel_val, sel_idx, out, cap);

    scatter_out<<<B_SZ * KEEP, 256, 0, stream>>>(sel_val, sel_idx, Wcon, out);
}

// Round 2
// 804.255 us; speedup vs baseline: 2.2055x; 2.2055x over previous
//
#include <hip/hip_runtime.h>

#define B_SZ 4
#define CIN 1024
#define DHI 2048
#define TT 8192
#define KEEP 512
#define OUT_ELEMS (B_SZ*CIN*TT)            // 33554432
#define SPARSE_PER_B (DHI*TT)              // 16777216
#define THRESH 3.0f
#define EPS_SEL 1e-4f
#define BORDER_CAP 64

// Staged bf16 hi/lo operand images live in the (not-yet-written) sparse region
// of d_out, overwritten later by fill_kernel. Offsets in floats.
#define AST_F ((size_t)OUT_ELEMS)                  // A staged: 8 MB
#define BST_F (AST_F + (size_t)2*1024*1024)        // B staged: 128 MB

typedef short bf16x8 __attribute__((ext_vector_type(8)));
typedef float f32x4 __attribute__((ext_vector_type(4)));

__device__ __forceinline__ unsigned short f2bf(float x) {
    unsigned u = __float_as_uint(x);
    return (unsigned short)((u + 0x7fffu + ((u >> 16) & 1u)) >> 16);
}
__device__ __forceinline__ float bf2f(unsigned short h) {
    return __uint_as_float(((unsigned)h) << 16);
}
__device__ __forceinline__ void gload16(const void* g, void* l) {
    __builtin_amdgcn_global_load_lds((const __attribute__((address_space(1))) void*)g,
                                     (__attribute__((address_space(3))) void*)l, 16, 0, 0);
}

// counters: [0..3] cand cnt, [4..7] sel cnt, [8..11] border cnt, [12..15] kth bits
#define WS_COUNTERS 0
#define WS_SELV 256
#define WS_SELI (256 + 8192)
#define WS_BCIDX (256 + 16384)
#define WS_BVAL (256 + 16384 + 1024)
#define WS_CAND (256 + 16384 + 2048)

// ---------------- convert A: W_exp [2048][1024] fp32 -> swizzled hi/lo tiles ---
// chunk (DB,KS): 128 rows(d) x 256B: [hi 64k | lo 64k], 16B slot P holds logical
// slot L = P ^ (r&15); L<8: hi octet L; L>=8: lo octet L-8.
__global__ __launch_bounds__(256) void convert_A(const float* __restrict__ Wexp,
                                                 float* __restrict__ outbuf,
                                                 unsigned* __restrict__ counters) {
    const int DB = blockIdx.x >> 4, KS = blockIdx.x & 15;
    char* dst = (char*)(outbuf + AST_F) + (size_t)blockIdx.x * 32768;
    for (int it = 0; it < 8; ++it) {
        int slot = threadIdx.x + it * 256;      // 0..2047
        int r = slot >> 4, P = slot & 15;
        int L = P ^ (r & 15);
        int part = L >> 3, oct = L & 7;
        const float* src = Wexp + (size_t)(DB * 128 + r) * CIN + KS * 64 + oct * 8;
        unsigned short v[8] __attribute__((aligned(16)));
#pragma unroll
        for (int j = 0; j < 8; ++j) {
            float xv = src[j];
            unsigned short hi = f2bf(xv);
            v[j] = part ? f2bf(xv - bf2f(hi)) : hi;
        }
        *(bf16x8*)(dst + r * 256 + P * 16) = *(const bf16x8*)v;
    }
    if (blockIdx.x == 0 && threadIdx.x < 32) counters[threadIdx.x] = 0u;
}

// ---------------- convert B: x [b][1024 k][8192 t] -> transposed swizzled tiles -
// chunk (b,TB,KS): 128 rows(t) x 256B, same slot scheme keyed on t&15.
__global__ __launch_bounds__(256) void convert_B(const float* __restrict__ x,
                                                 float* __restrict__ outbuf) {
    const int TB = blockIdx.x, KS = blockIdx.y, b = blockIdx.z;
    char* dst = (char*)(outbuf + BST_F) + ((size_t)((b * 64 + TB) * 16 + KS)) * 32768;
    const float* xb = x + (size_t)b * CIN * TT;
    for (int it = 0; it < 4; ++it) {
        int task = threadIdx.x + it * 256;      // 0..1023
        int t = task & 127, L = task >> 7;      // L in 0..7
        const float* src = xb + (size_t)(KS * 64 + L * 8) * TT + TB * 128 + t;
        unsigned short hi[8] __attribute__((aligned(16)));
        unsigned short lo[8] __attribute__((aligned(16)));
#pragma unroll
        for (int j = 0; j < 8; ++j) {
            float xv = src[(size_t)j * TT];
            hi[j] = f2bf(xv);
            lo[j] = f2bf(xv - bf2f(hi[j]));
        }
        int Ph = L ^ (t & 15), Pl = (L + 8) ^ (t & 15);
        *(bf16x8*)(dst + t * 256 + Ph * 16) = *(const bf16x8*)hi;
        *(bf16x8*)(dst + t * 256 + Pl * 16) = *(const bf16x8*)lo;
    }
}

// ---------------- GEMM: bf16x3 MFMA, 128x128 tile, 4 waves x 64x64, BK=64 ------
__global__ __launch_bounds__(256) void gemm_bf16x3(const float* __restrict__ staged,
                                                   const float* __restrict__ bexp,
                                                   float* __restrict__ cand_val,
                                                   unsigned* __restrict__ cand_idx,
                                                   unsigned* __restrict__ counters,
                                                   int cap) {
    __shared__ char lds[65536];
    __shared__ float s_cv[512];
    __shared__ unsigned s_ci[512];
    __shared__ unsigned s_cnt, s_base;

    const int tid = threadIdx.x;
    const int l = tid & 63, w = tid >> 6;
    const int wm = w >> 1, wn = w & 1;
    const int bx = blockIdx.x, by = blockIdx.y, b = blockIdx.z;

    const char* Achunk0 = (const char*)(staged + AST_F) + (size_t)(by * 16) * 32768;
    const char* Bchunk0 = (const char*)(staged + BST_F) + (size_t)((b * 64 + bx) * 16) * 32768;

    f32x4 acc[4][4];
#pragma unroll
    for (int i = 0; i < 4; ++i)
#pragma unroll
        for (int j = 0; j < 4; ++j) acc[i][j] = (f32x4)0.f;

    const char* ldsb = &lds[0];
    for (int ks = 0; ks < 16; ++ks) {
        const char* gsrc;
        const char* ldst;
        if (w < 2) {
            gsrc = Achunk0 + (size_t)ks * 32768 + w * 16384;
            ldst = ldsb + w * 16384;
        } else {
            gsrc = Bchunk0 + (size_t)ks * 32768 + (w - 2) * 16384;
            ldst = ldsb + 32768 + (w - 2) * 16384;
        }
#pragma unroll
        for (int n = 0; n < 16; ++n)
            gload16(gsrc + n * 1024 + l * 16, (void*)(ldst + n * 1024));
        asm volatile("s_waitcnt vmcnt(0)" ::: "memory");
        __syncthreads();

#pragma unroll
        for (int s = 0; s < 2; ++s) {
            bf16x8 af[4][2], bfr[4][2];
#pragma unroll
            for (int i = 0; i < 4; ++i) {
                int r = wm * 64 + i * 16 + (l & 15);
#pragma unroll
                for (int p = 0; p < 2; ++p) {
                    int L = p * 8 + s * 4 + (l >> 4);
                    int P = L ^ (r & 15);
                    af[i][p] = *(const bf16x8*)(ldsb + r * 256 + P * 16);
                }
            }
#pragma unroll
            for (int j = 0; j < 4; ++j) {
                int r = wn * 64 + j * 16 + (l & 15);
#pragma unroll
                for (int p = 0; p < 2; ++p) {
                    int L = p * 8 + s * 4 + (l >> 4);
                    int P = L ^ (r & 15);
                    bfr[j][p] = *(const bf16x8*)(ldsb + 32768 + r * 256 + P * 16);
                }
            }
#pragma unroll
            for (int i = 0; i < 4; ++i)
#pragma unroll
                for (int j = 0; j < 4; ++j) {
                    acc[i][j] = __builtin_amdgcn_mfma_f32_16x16x32_bf16(af[i][0], bfr[j][0], acc[i][j], 0, 0, 0);
                    acc[i][j] = __builtin_amdgcn_mfma_f32_16x16x32_bf16(af[i][1], bfr[j][0], acc[i][j], 0, 0, 0);
                    acc[i][j] = __builtin_amdgcn_mfma_f32_16x16x32_bf16(af[i][0], bfr[j][1], acc[i][j], 0, 0, 0);
                }
        }
        __syncthreads();
    }

    // Epilogue: bias + threshold candidate collection.
    if (tid == 0) s_cnt = 0;
    __syncthreads();
#pragma unroll
    for (int i = 0; i < 4; ++i)
#pragma unroll
        for (int j = 0; j < 4; ++j)
#pragma unroll
            for (int q = 0; q < 4; ++q) {
                int d = by * 128 + wm * 64 + i * 16 + (l >> 4) * 4 + q;
                int t = bx * 128 + wn * 64 + j * 16 + (l & 15);
                float val = acc[i][j][q] + bexp[d];
                if (val > THRESH) {
                    unsigned p = atomicAdd(&s_cnt, 1u);
                    if (p < 512u) {
                        s_cv[p] = val;
                        s_ci[p] = (unsigned)(d * TT + t);
                    }
                }
            }
    __syncthreads();
    unsigned n = s_cnt < 512u ? s_cnt : 512u;
    if (tid == 0) s_base = atomicAdd(&counters[b], n);
    __syncthreads();
    unsigned base = s_base;
    for (unsigned i = tid; i < n; i += 256u) {
        unsigned pos = base + i;
        if (pos < (unsigned)cap) {
            cand_val[(size_t)b * cap + pos] = s_cv[i];
            cand_idx[(size_t)b * cap + pos] = s_ci[i];
        }
    }
}

// ---------------- fill: bias into dense out, zeros into sparse region ----------
__global__ __launch_bounds__(256) void fill_kernel(const float* __restrict__ bcon,
                                                   float* __restrict__ out) {
    const int OUT4 = OUT_ELEMS / 4;
    const int TOT4 = (OUT_ELEMS + B_SZ * SPARSE_PER_B) / 4;
    float4* o4 = (float4*)out;
    for (int i = blockIdx.x * blockDim.x + threadIdx.x; i < TOT4;
         i += gridDim.x * blockDim.x) {
        float4 v;
        if (i < OUT4) {
            float bc = bcon[(i >> 11) & (CIN - 1)];
            v = make_float4(bc, bc, bc, bc);
        } else {
            v = make_float4(0.f, 0.f, 0.f, 0.f);
        }
        o4[i] = v;
    }
}

// ---------------- exact 32-bit kth (rank-512) via 4-pass radix ------------------
__global__ __launch_bounds__(256) void select_kth(const float* __restrict__ cand_val,
                                                  unsigned* __restrict__ counters,
                                                  float* __restrict__ sel_val,
                                                  unsigned* __restrict__ sel_idx,
                                                  int cap) {
    const int b = blockIdx.x;
    const int tid = threadIdx.x;
    const float* cv = cand_val + (size_t)b * cap;
    unsigned nc = counters[b];
    int n = (int)(nc < (unsigned)cap ? nc : (unsigned)cap);

    // zero sel arrays (tail slots must be 0 for scatter skip)
    for (int i = tid; i < KEEP; i += 256) {
        sel_val[b * KEEP + i] = 0.f;
        sel_idx[b * KEEP + i] = 0u;
    }

    __shared__ unsigned hist[256];
    __shared__ unsigned s_sel, s_rem;
    unsigned prefix = 0;
    int remaining = KEEP;
    for (int pass = 0; pass < 4; ++pass) {
        int shift = 24 - pass * 8;
        hist[tid] = 0;
        __syncthreads();
        for (int i = tid; i < n; i += 256) {
            unsigned u = __float_as_uint(cv[i]);
            unsigned hi = (pass == 0) ? 0u : (u >> (shift + 8));
            if (hi == prefix) atomicAdd(&hist[(u >> shift) & 255u], 1u);
        }
        __syncthreads();
        if (tid == 0) {
            int rem = remaining;
            unsigned selb = 0;
            for (int byte = 255; byte >= 0; --byte) {
                int c = (int)hist[byte];
                if (c >= rem) { selb = (unsigned)byte; break; }
                rem -= c;
            }
            s_sel = selb;
            s_rem = (unsigned)rem;
        }
        __syncthreads();
        prefix = (prefix << 8) | s_sel;
        remaining = (int)s_rem;
        __syncthreads();
    }
    if (tid == 0) counters[12 + b] = prefix;   // exact bits of approx-kth
}

// ---------------- classify: sure-in emit, borderline collect --------------------
__global__ __launch_bounds__(256) void classify(const float* __restrict__ cand_val,
                                                const unsigned* __restrict__ cand_idx,
                                                unsigned* __restrict__ counters,
                                                float* __restrict__ sel_val,
                                                unsigned* __restrict__ sel_idx,
                                                unsigned* __restrict__ border_cidx,
                                                float* __restrict__ d_out,
                                                int cap) {
    const int b = blockIdx.x;
    const int tid = threadIdx.x;
    const float* cv = cand_val + (size_t)b * cap;
    const unsigned* ci = cand_idx + (size_t)b * cap;
    unsigned nc = counters[b];
    int n = (int)(nc < (unsigned)cap ? nc : (unsigned)cap);
    float kth = __uint_as_float(counters[12 + b]);
    float hi = kth + EPS_SEL, lo = kth - EPS_SEL;
    float* sparse = d_out + (size_t)OUT_ELEMS + (size_t)b * SPARSE_PER_B;

    for (int i = tid; i < n; i += 256) {
        float v = cv[i];
        if (v > hi) {
            unsigned p = atomicAdd(&counters[4 + b], 1u);
            unsigned idx = ci[i];
            sel_val[b * KEEP + p] = v;
            sel_idx[b * KEEP + p] = idx;
            sparse[idx] = v;
        } else if (v >= lo) {
            unsigned q = atomicAdd(&counters[8 + b], 1u);
            if (q < BORDER_CAP) border_cidx[b * BORDER_CAP + q] = (unsigned)i;
        }
    }
}

// ---------------- exact fp32 recompute of borderline candidates -----------------
__global__ __launch_bounds__(256) void recompute(const float* __restrict__ x,
                                                 const float* __restrict__ Wexp,
                                                 const float* __restrict__ bexp,
                                                 const unsigned* __restrict__ cand_idx,
                                                 const unsigned* __restrict__ counters,
                                                 const unsigned* __restrict__ border_cidx,
                                                 float* __restrict__ border_val,
                                                 int cap) {
    const int b = blockIdx.y, j = blockIdx.x;
    unsigned nb = counters[8 + b];
    if (nb > BORDER_CAP) nb = BORDER_CAP;
    if ((unsigned)j >= nb) return;
    unsigned cidx = border_cidx[b * BORDER_CAP + j];
    unsigned idx = cand_idx[(size_t)b * cap + cidx];
    int d = (int)(idx >> 13), t = (int)(idx & 8191u);
    const float* xb = x + (size_t)b * CIN * TT;
    const float* wr = Wexp + (size_t)d * CIN;
    float ssum = 0.f;
    for (int k = threadIdx.x; k < CIN; k += 256)
        ssum += xb[(size_t)k * TT + t] * wr[k];
    __shared__ float red[256];
    red[threadIdx.x] = ssum;
    __syncthreads();
    for (int off = 128; off > 0; off >>= 1) {
        if (threadIdx.x < off) red[threadIdx.x] += red[threadIdx.x + off];
        __syncthreads();
    }
    if (threadIdx.x == 0) border_val[b * BORDER_CAP + j] = red[0] + bexp[d];
}

// ---------------- finalize: rank borderline exactly, fill remaining slots -------
__global__ __launch_bounds__(256) void finalize(unsigned* __restrict__ counters,
                                                const unsigned* __restrict__ border_cidx,
                                                const float* __restrict__ border_val,
                                                const unsigned* __restrict__ cand_idx,
                                                float* __restrict__ sel_val,
                                                unsigned* __restrict__ sel_idx,
                                                float* __restrict__ d_out,
                                                int cap) {
    const int b = blockIdx.x;
    const int tid = threadIdx.x;
    int nsure = (int)counters[4 + b];
    int nb = (int)counters[8 + b];
    if (nb > BORDER_CAP) nb = BORDER_CAP;
    int r = KEEP - nsure;
    if (r > nb) r = nb;
    if (r < 0) r = 0;
    if (tid < nb) {
        float v = border_val[b * BORDER_CAP + tid];
        unsigned idx = cand_idx[(size_t)b * cap + border_cidx[b * BORDER_CAP + tid]];
        int rank = 0;
        for (int j = 0; j < nb; ++j) {
            float vj = border_val[b * BORDER_CAP + j];
            unsigned ij = cand_idx[(size_t)b * cap + border_cidx[b * BORDER_CAP + j]];
            if (vj > v || (vj == v && ij < idx)) rank++;
        }
        if (rank < r) {
            int p = nsure + rank;
            sel_val[b * KEEP + p] = v;
            sel_idx[b * KEEP + p] = idx;
            d_out[(size_t)OUT_ELEMS + (size_t)b * SPARSE_PER_B + idx] = v;
        }
    }
}

// ---------------- scatter: out[b,:,t] += v * W_con[:,d] -------------------------
__global__ __launch_bounds__(256) void scatter_out(const float* __restrict__ sel_val,
                                                   const unsigned* __restrict__ sel_idx,
                                                   const float* __restrict__ Wcon,
                                                   float* __restrict__ out) {
    const int b = blockIdx.x >> 9;
    const int j = blockIdx.x & 511;
    const float v = sel_val[b * KEEP + j];
    if (v == 0.f) return;
    const unsigned idx = sel_idx[b * KEEP + j];
    const int d = (int)(idx >> 13);
    const int t = (int)(idx & 8191u);
    const int tid = threadIdx.x;
#pragma unroll
    for (int i = 0; i < 4; ++i) {
        int c = tid + i * 256;
        float wv = Wcon[(size_t)c * DHI + d];
        atomicAdd(&out[(((size_t)(b * CIN + c)) << 13) + t], v * wv);
    }
}

extern "C" void kernel_launch(void* const* d_in, const int* in_sizes, int n_in,
                              void* d_out, int out_size, void* d_ws, size_t ws_size,
                              hipStream_t stream) {
    const float* x    = (const float*)d_in[0];
    const float* Wexp = (const float*)d_in[1];
    const float* bexp = (const float*)d_in[2];
    const float* Wcon = (const float*)d_in[3];
    const float* bcon = (const float*)d_in[4];
    float* out = (float*)d_out;

    unsigned* counters = (unsigned*)((char*)d_ws + WS_COUNTERS);
    float*    sel_val  = (float*)((char*)d_ws + WS_SELV);
    unsigned* sel_idx  = (unsigned*)((char*)d_ws + WS_SELI);
    unsigned* border_cidx = (unsigned*)((char*)d_ws + WS_BCIDX);
    float*    border_val  = (float*)((char*)d_ws + WS_BVAL);
    char* cand_base = (char*)d_ws + WS_CAND;
    size_t remain = ws_size - WS_CAND;
    size_t cap_sz = remain / ((size_t)B_SZ * 8);
    int cap = (int)(cap_sz < (size_t)65536 ? cap_sz : (size_t)65536);
    float*    cand_val = (float*)cand_base;
    unsigned* cand_idx = (unsigned*)(cand_base + (size_t)B_SZ * cap * 4);

    // 1) stage split-precision operands into d_out's sparse region
    convert_A<<<256, 256, 0, stream>>>(Wexp, out, counters);
    convert_B<<<dim3(64, 16, 4), 256, 0, stream>>>(x, out);

    // 2) MFMA bf16x3 GEMM + threshold candidate collection
    gemm_bf16x3<<<dim3(64, 16, 4), 256, 0, stream>>>(out, bexp, cand_val, cand_idx,
                                                     counters, cap);

    // 3) overwrite d_out with bias / zeros (staged data no longer needed)
    fill_kernel<<<4096, 256, 0, stream>>>(bcon, out);

    // 4) selection: approx kth -> sure-in emit -> exact borderline resolution
    select_kth<<<B_SZ, 256, 0, stream>>>(cand_val, counters, sel_val, sel_idx, cap);
    classify<<<B_SZ, 256, 0, stream>>>(cand_val, cand_idx, counters, sel_val, sel_idx,
                                       border_cidx, out, cap);
    recompute<<<dim3(BORDER_CAP, B_SZ), 256, 0, stream>>>(x, Wexp, bexp, cand_idx,
                                                          counters, border_cidx,
                                                          border_val, cap);
    finalize<<<B_SZ, 256, 0, stream>>>(counters, border_cidx, border_val, cand_idx,
                                       sel_val, sel_idx, out, cap);

    // 5) sparse second GEMM as rank-1 column scatters
    scatter_out<<<B_SZ * KEEP, 256, 0, stream>>>(sel_val, sel_idx, Wcon, out);
}

// Round 3
// 770.352 us; speedup vs baseline: 2.3026x; 1.0440x over previous
//
#include <hip/hip_runtime.h>

#define B_SZ 4
#define CIN 1024
#define DHI 2048
#define TT 8192
#define KEEP 512
#define OUT_ELEMS (B_SZ*CIN*TT)            // 33554432
#define SPARSE_PER_B (DHI*TT)              // 16777216
#define THRESH 3.0f
#define EPS_SEL 1e-4f
#define BORDER_CAP 64

// Staged bf16 hi/lo operand images live in the (not-yet-written) sparse region
// of d_out, overwritten later by zero_sparse. Offsets in floats.
#define AST_F ((size_t)OUT_ELEMS)                  // A staged: 8 MB
#define BST_F (AST_F + (size_t)2*1024*1024)        // B staged: 134 MB

typedef short bf16x8 __attribute__((ext_vector_type(8)));
typedef float f32x4 __attribute__((ext_vector_type(4)));

__device__ __forceinline__ unsigned short f2bf(float x) {
    unsigned u = __float_as_uint(x);
    return (unsigned short)((u + 0x7fffu + ((u >> 16) & 1u)) >> 16);
}
__device__ __forceinline__ float bf2f(unsigned short h) {
    return __uint_as_float(((unsigned)h) << 16);
}
__device__ __forceinline__ void gload16(const void* g, void* l) {
    __builtin_amdgcn_global_load_lds((const __attribute__((address_space(1))) void*)g,
                                     (__attribute__((address_space(3))) void*)l, 16, 0, 0);
}

// ws layout: counters[0..31] | sel_val[B*512] | sel_idx[B*512] | cand arrays
#define WS_COUNTERS 0
#define WS_SELV 256
#define WS_SELI (256 + 8192)
#define WS_CAND (256 + 16384)

// ---------------- convert A: W_exp [2048][1024] fp32 -> swizzled hi/lo tiles ---
__global__ __launch_bounds__(256) void convert_A(const float* __restrict__ Wexp,
                                                 float* __restrict__ outbuf,
                                                 unsigned* __restrict__ counters) {
    const int DB = blockIdx.x >> 4, KS = blockIdx.x & 15;
    char* dst = (char*)(outbuf + AST_F) + (size_t)blockIdx.x * 32768;
    for (int it = 0; it < 8; ++it) {
        int slot = threadIdx.x + it * 256;      // 0..2047
        int r = slot >> 4, P = slot & 15;
        int L = P ^ (r & 15);
        int part = L >> 3, oct = L & 7;
        const float* src = Wexp + (size_t)(DB * 128 + r) * CIN + KS * 64 + oct * 8;
        unsigned short v[8] __attribute__((aligned(16)));
#pragma unroll
        for (int j = 0; j < 8; ++j) {
            float xv = src[j];
            unsigned short hi = f2bf(xv);
            v[j] = part ? f2bf(xv - bf2f(hi)) : hi;
        }
        *(bf16x8*)(dst + r * 256 + P * 16) = *(const bf16x8*)v;
    }
    if (blockIdx.x == 0 && threadIdx.x < 32) counters[threadIdx.x] = 0u;
}

// ---------------- convert B: x [b][1024 k][8192 t] -> transposed swizzled tiles -
__global__ __launch_bounds__(256) void convert_B(const float* __restrict__ x,
                                                 float* __restrict__ outbuf) {
    const int TB = blockIdx.x, KS = blockIdx.y, b = blockIdx.z;
    char* dst = (char*)(outbuf + BST_F) + ((size_t)((b * 64 + TB) * 16 + KS)) * 32768;
    const float* xb = x + (size_t)b * CIN * TT;
    for (int it = 0; it < 4; ++it) {
        int task = threadIdx.x + it * 256;      // 0..1023
        int t = task & 127, L = task >> 7;      // L in 0..7
        const float* src = xb + (size_t)(KS * 64 + L * 8) * TT + TB * 128 + t;
        unsigned short hi[8] __attribute__((aligned(16)));
        unsigned short lo[8] __attribute__((aligned(16)));
#pragma unroll
        for (int j = 0; j < 8; ++j) {
            float xv = src[(size_t)j * TT];
            hi[j] = f2bf(xv);
            lo[j] = f2bf(xv - bf2f(hi[j]));
        }
        int Ph = L ^ (t & 15), Pl = (L + 8) ^ (t & 15);
        *(bf16x8*)(dst + t * 256 + Ph * 16) = *(const bf16x8*)hi;
        *(bf16x8*)(dst + t * 256 + Pl * 16) = *(const bf16x8*)lo;
    }
}

// ---------------- GEMM: bf16x3 MFMA, 128x128 tile, 4 waves x 64x64, BK=64 ------
__global__ __launch_bounds__(256) void gemm_bf16x3(const float* __restrict__ staged,
                                                   const float* __restrict__ bexp,
                                                   float* __restrict__ cand_val,
                                                   unsigned* __restrict__ cand_idx,
                                                   unsigned* __restrict__ counters,
                                                   int cap) {
    __shared__ char lds[65536];
    __shared__ float s_cv[512];
    __shared__ unsigned s_ci[512];
    __shared__ unsigned s_cnt, s_base;

    const int tid = threadIdx.x;
    const int l = tid & 63, w = tid >> 6;
    const int wm = w >> 1, wn = w & 1;
    const int bx = blockIdx.x, by = blockIdx.y, b = blockIdx.z;

    const char* Achunk0 = (const char*)(staged + AST_F) + (size_t)(by * 16) * 32768;
    const char* Bchunk0 = (const char*)(staged + BST_F) + (size_t)((b * 64 + bx) * 16) * 32768;

    f32x4 acc[4][4];
#pragma unroll
    for (int i = 0; i < 4; ++i)
#pragma unroll
        for (int j = 0; j < 4; ++j) acc[i][j] = (f32x4)0.f;

    const char* ldsb = &lds[0];
    for (int ks = 0; ks < 16; ++ks) {
        const char* gsrc;
        const char* ldst;
        if (w < 2) {
            gsrc = Achunk0 + (size_t)ks * 32768 + w * 16384;
            ldst = ldsb + w * 16384;
        } else {
            gsrc = Bchunk0 + (size_t)ks * 32768 + (w - 2) * 16384;
            ldst = ldsb + 32768 + (w - 2) * 16384;
        }
#pragma unroll
        for (int n = 0; n < 16; ++n)
            gload16(gsrc + n * 1024 + l * 16, (void*)(ldst + n * 1024));
        asm volatile("s_waitcnt vmcnt(0)" ::: "memory");
        __syncthreads();

#pragma unroll
        for (int s = 0; s < 2; ++s) {
            bf16x8 af[4][2], bfr[4][2];
#pragma unroll
            for (int i = 0; i < 4; ++i) {
                int r = wm * 64 + i * 16 + (l & 15);
#pragma unroll
                for (int p = 0; p < 2; ++p) {
                    int L = p * 8 + s * 4 + (l >> 4);
                    int P = L ^ (r & 15);
                    af[i][p] = *(const bf16x8*)(ldsb + r * 256 + P * 16);
                }
            }
#pragma unroll
            for (int j = 0; j < 4; ++j) {
                int r = wn * 64 + j * 16 + (l & 15);
#pragma unroll
                for (int p = 0; p < 2; ++p) {
                    int L = p * 8 + s * 4 + (l >> 4);
                    int P = L ^ (r & 15);
                    bfr[j][p] = *(const bf16x8*)(ldsb + 32768 + r * 256 + P * 16);
                }
            }
#pragma unroll
            for (int i = 0; i < 4; ++i)
#pragma unroll
                for (int j = 0; j < 4; ++j) {
                    acc[i][j] = __builtin_amdgcn_mfma_f32_16x16x32_bf16(af[i][0], bfr[j][0], acc[i][j], 0, 0, 0);
                    acc[i][j] = __builtin_amdgcn_mfma_f32_16x16x32_bf16(af[i][1], bfr[j][0], acc[i][j], 0, 0, 0);
                    acc[i][j] = __builtin_amdgcn_mfma_f32_16x16x32_bf16(af[i][0], bfr[j][1], acc[i][j], 0, 0, 0);
                }
        }
        __syncthreads();
    }

    // Epilogue: bias + threshold candidate collection.
    if (tid == 0) s_cnt = 0;
    __syncthreads();
#pragma unroll
    for (int i = 0; i < 4; ++i)
#pragma unroll
        for (int j = 0; j < 4; ++j)
#pragma unroll
            for (int q = 0; q < 4; ++q) {
                int d = by * 128 + wm * 64 + i * 16 + (l >> 4) * 4 + q;
                int t = bx * 128 + wn * 64 + j * 16 + (l & 15);
                float val = acc[i][j][q] + bexp[d];
                if (val > THRESH) {
                    unsigned p = atomicAdd(&s_cnt, 1u);
                    if (p < 512u) {
                        s_cv[p] = val;
                        s_ci[p] = (unsigned)(d * TT + t);
                    }
                }
            }
    __syncthreads();
    unsigned n = s_cnt < 512u ? s_cnt : 512u;
    if (tid == 0) s_base = atomicAdd(&counters[b], n);
    __syncthreads();
    unsigned base = s_base;
    for (unsigned i = tid; i < n; i += 256u) {
        unsigned pos = base + i;
        if (pos < (unsigned)cap) {
            cand_val[(size_t)b * cap + pos] = s_cv[i];
            cand_idx[(size_t)b * cap + pos] = s_ci[i];
        }
    }
}

// ---------------- zero the sparse output region (268 MB) ------------------------
__global__ __launch_bounds__(256) void zero_sparse(float* __restrict__ out) {
    const size_t N4 = (size_t)B_SZ * SPARSE_PER_B / 4;
    float4* o4 = (float4*)(out + (size_t)OUT_ELEMS);
    const float4 z = make_float4(0.f, 0.f, 0.f, 0.f);
    for (size_t i = blockIdx.x * blockDim.x + threadIdx.x; i < N4;
         i += (size_t)gridDim.x * blockDim.x)
        o4[i] = z;
}

// ---------------- merged selection: kth radix + classify + exact border + emit --
__global__ __launch_bounds__(256) void select_all(const float* __restrict__ cand_val,
                                                  const unsigned* __restrict__ cand_idx,
                                                  const unsigned* __restrict__ counters,
                                                  float* __restrict__ sel_val,
                                                  unsigned* __restrict__ sel_idx,
                                                  const float* __restrict__ x,
                                                  const float* __restrict__ Wexp,
                                                  const float* __restrict__ bexp,
                                                  float* __restrict__ d_out,
                                                  int cap) {
    const int b = blockIdx.x;
    const int tid = threadIdx.x;
    const float* cv = cand_val + (size_t)b * cap;
    const unsigned* ci = cand_idx + (size_t)b * cap;
    unsigned nc = counters[b];
    int n = (int)(nc < (unsigned)cap ? nc : (unsigned)cap);

    __shared__ unsigned hist[256];
    __shared__ float red[256];
    __shared__ unsigned s_sel, s_rem, s_scnt, s_bcnt;
    __shared__ float s_bv[BORDER_CAP];
    __shared__ unsigned s_bi[BORDER_CAP];

    for (int i = tid; i < KEEP; i += 256) {
        sel_val[b * KEEP + i] = 0.f;
        sel_idx[b * KEEP + i] = 0u;
    }

    // 4-pass radix: exact 32 bits of the approx rank-512 value (all vals > 3 > 0)
    unsigned prefix = 0;
    int remaining = KEEP;
    for (int pass = 0; pass < 4; ++pass) {
        int shift = 24 - pass * 8;
        hist[tid] = 0;
        __syncthreads();
        for (int i = tid; i < n; i += 256) {
            unsigned u = __float_as_uint(cv[i]);
            unsigned hb = (pass == 0) ? 0u : (u >> (shift + 8));
            if (hb == prefix) atomicAdd(&hist[(u >> shift) & 255u], 1u);
        }
        __syncthreads();
        if (tid == 0) {
            int rem = remaining;
            unsigned selb = 0;
            for (int byte = 255; byte >= 0; --byte) {
                int c = (int)hist[byte];
                if (c >= rem) { selb = (unsigned)byte; break; }
                rem -= c;
            }
            s_sel = selb;
            s_rem = (unsigned)rem;
        }
        __syncthreads();
        prefix = (prefix << 8) | s_sel;
        remaining = (int)s_rem;
        __syncthreads();
    }

    // classify: sure-in emit directly; borderline collect
    if (tid == 0) { s_scnt = 0; s_bcnt = 0; }
    __syncthreads();
    const float kth = __uint_as_float(prefix);
    const float hiv = kth + EPS_SEL, lov = kth - EPS_SEL;
    float* sparse = d_out + (size_t)OUT_ELEMS + (size_t)b * SPARSE_PER_B;
    for (int i = tid; i < n; i += 256) {
        float v = cv[i];
        if (v > hiv) {
            unsigned p = atomicAdd(&s_scnt, 1u);
            unsigned idx = ci[i];
            sel_val[b * KEEP + p] = v;
            sel_idx[b * KEEP + p] = idx;
            sparse[idx] = v;
        } else if (v >= lov) {
            unsigned q = atomicAdd(&s_bcnt, 1u);
            if (q < BORDER_CAP) s_bi[q] = (unsigned)i;
        }
    }
    __syncthreads();
    int nsure = (int)s_scnt;
    int nb = (int)(s_bcnt < BORDER_CAP ? s_bcnt : BORDER_CAP);

    // exact fp32 recompute of borderline candidates (typically 0-2)
    const float* xb = x + (size_t)b * CIN * TT;
    for (int j = 0; j < nb; ++j) {
        unsigned idx = ci[s_bi[j]];
        int d = (int)(idx >> 13), t = (int)(idx & 8191u);
        const float* wr = Wexp + (size_t)d * CIN;
        float ssum = 0.f;
        for (int k = tid; k < CIN; k += 256)
            ssum += xb[(size_t)k * TT + t] * wr[k];
        red[tid] = ssum;
        __syncthreads();
        for (int off = 128; off > 0; off >>= 1) {
            if (tid < off) red[tid] += red[tid + off];
            __syncthreads();
        }
        if (tid == 0) s_bv[j] = red[0] + bexp[d];
        __syncthreads();
    }

    // rank borderline exactly, fill remaining slots
    int r = KEEP - nsure;
    if (r > nb) r = nb;
    if (r < 0) r = 0;
    if (tid < nb) {
        float v = s_bv[tid];
        unsigned idx = ci[s_bi[tid]];
        int rank = 0;
        for (int j = 0; j < nb; ++j) {
            float vj = s_bv[j];
            unsigned ij = ci[s_bi[j]];
            if (vj > v || (vj == v && ij < idx)) rank++;
        }
        if (rank < r) {
            int p = nsure + rank;
            sel_val[b * KEEP + p] = v;
            sel_idx[b * KEEP + p] = idx;
            sparse[idx] = v;
        }
    }
}

// ---------------- fused dense fill + sparse second GEMM -------------------------
// out[b,c,t] = bcon[c] + sum_{j: t_j==t} v_j * Wcon[c][d_j]; pure coalesced write.
__global__ __launch_bounds__(256) void fill_dense(const float* __restrict__ bcon,
                                                  const float* __restrict__ Wcon,
                                                  const float* __restrict__ sel_val,
                                                  const unsigned* __restrict__ sel_idx,
                                                  float* __restrict__ out) {
    const int tcb = blockIdx.x;          // 128 chunks of 64 t
    const int cb  = blockIdx.y;          // 4 chunks of 256 c
    const int b   = blockIdx.z;
    const int tid = threadIdx.x;
    const int t0 = tcb * 64, c0 = cb * 256;

    __shared__ float s_v[BORDER_CAP];
    __shared__ int s_t[BORDER_CAP], s_d[BORDER_CAP];
    __shared__ unsigned s_ne;
    if (tid == 0) s_ne = 0;
    __syncthreads();
    for (int i = tid; i < KEEP; i += 256) {
        float v = sel_val[b * KEEP + i];
        if (v != 0.f) {
            unsigned idx = sel_idx[b * KEEP + i];
            int t = (int)(idx & 8191u);
            if (t >= t0 && t < t0 + 64) {
                unsigned p = atomicAdd(&s_ne, 1u);
                if (p < BORDER_CAP) {
                    s_v[p] = v;
                    s_t[p] = t - t0;
                    s_d[p] = (int)(idx >> 13);
                }
            }
        }
    }
    __syncthreads();
    const int ne = (int)(s_ne < BORDER_CAP ? s_ne : BORDER_CAP);
    const int lane16 = tid & 15;         // t-quad within chunk
    const int cr = tid >> 4;             // 16 c-rows in flight

    for (int it = 0; it < 16; ++it) {
        int c = c0 + it * 16 + cr;
        float bias = bcon[c];
        float v0 = bias, v1 = bias, v2 = bias, v3 = bias;
        for (int j = 0; j < ne; ++j) {
            int tj = s_t[j];
            if ((tj >> 2) == lane16) {
                float add = s_v[j] * Wcon[(size_t)c * DHI + s_d[j]];
                int q = tj & 3;
                if (q == 0) v0 += add;
                else if (q == 1) v1 += add;
                else if (q == 2) v2 += add;
                else v3 += add;
            }
        }
        *(float4*)(&out[(((size_t)(b * CIN + c)) << 13) + t0 + lane16 * 4]) =
            make_float4(v0, v1, v2, v3);
    }
}

extern "C" void kernel_launch(void* const* d_in, const int* in_sizes, int n_in,
                              void* d_out, int out_size, void* d_ws, size_t ws_size,
                              hipStream_t stream) {
    const float* x    = (const float*)d_in[0];
    const float* Wexp = (const float*)d_in[1];
    const float* bexp = (const float*)d_in[2];
    const float* Wcon = (const float*)d_in[3];
    const float* bcon = (const float*)d_in[4];
    float* out = (float*)d_out;

    unsigned* counters = (unsigned*)((char*)d_ws + WS_COUNTERS);
    float*    sel_val  = (float*)((char*)d_ws + WS_SELV);
    unsigned* sel_idx  = (unsigned*)((char*)d_ws + WS_SELI);
    char* cand_base = (char*)d_ws + WS_CAND;
    size_t remain = ws_size - WS_CAND;
    size_t cap_sz = remain / ((size_t)B_SZ * 8);
    int cap = (int)(cap_sz < (size_t)65536 ? cap_sz : (size_t)65536);
    float*    cand_val = (float*)cand_base;
    unsigned* cand_idx = (unsigned*)(cand_base + (size_t)B_SZ * cap * 4);

    // 1) stage split-precision operands into d_out's sparse region
    convert_A<<<256, 256, 0, stream>>>(Wexp, out, counters);
    convert_B<<<dim3(64, 16, 4), 256, 0, stream>>>(x, out);

    // 2) MFMA bf16x3 GEMM + threshold candidate collection
    gemm_bf16x3<<<dim3(64, 16, 4), 256, 0, stream>>>(out, bexp, cand_val, cand_idx,
                                                     counters, cap);

    // 3) zero sparse output region (staging dead now)
    zero_sparse<<<2048, 256, 0, stream>>>(out);

    // 4) merged selection: approx kth -> sure emit -> exact borderline -> finalize
    select_all<<<B_SZ, 256, 0, stream>>>(cand_val, cand_idx, counters, sel_val,
                                         sel_idx, x, Wexp, bexp, out, cap);

    // 5) fused dense bias fill + sparse second GEMM (no atomics)
    fill_dense<<<dim3(128, 4, B_SZ), 256, 0, stream>>>(bcon, Wcon, sel_val, sel_idx, out);
}

// Round 5
// 732.875 us; speedup vs baseline: 2.4203x; 1.0511x over previous
//
#include <hip/hip_runtime.h>

#define B_SZ 4
#define CIN 1024
#define DHI 2048
#define TT 8192
#define KEEP 512
#define OUT_ELEMS (B_SZ*CIN*TT)            // 33554432
#define SPARSE_PER_B (DHI*TT)              // 16777216
#define THRESH 3.0f
#define EPS_SEL 1e-4f
#define BORDER_CAP 64

// A staged bf16 hi/lo image lives in the (not-yet-written) sparse region of
// d_out, overwritten later by zero_sparse. Offset in floats.
#define AST_F ((size_t)OUT_ELEMS)                  // A staged: 8 MB

typedef short bf16x8 __attribute__((ext_vector_type(8)));
typedef float f32x4 __attribute__((ext_vector_type(4)));

__device__ __forceinline__ unsigned short f2bf(float x) {
    unsigned u = __float_as_uint(x);
    return (unsigned short)((u + 0x7fffu + ((u >> 16) & 1u)) >> 16);
}
__device__ __forceinline__ float bf2f(unsigned short h) {
    return __uint_as_float(((unsigned)h) << 16);
}
__device__ __forceinline__ void gload16(const void* g, void* l) {
    __builtin_amdgcn_global_load_lds((const __attribute__((address_space(1))) void*)g,
                                     (__attribute__((address_space(3))) void*)l, 16, 0, 0);
}

// ws layout: counters[0..31] | sel_val[B*512] | sel_idx[B*512] | cand arrays
#define WS_COUNTERS 0
#define WS_SELV 256
#define WS_SELI (256 + 8192)
#define WS_CAND (256 + 16384)

// ---------------- convert A: W_exp [2048][1024] fp32 -> swizzled hi/lo tiles ---
// chunk (DB,KS): 128 rows(d) x 256B: [hi 64k | lo 64k], 16B slot P holds logical
// slot L = P ^ (r&15); L<8: hi octet L; L>=8: lo octet L-8.
__global__ __launch_bounds__(256) void convert_A(const float* __restrict__ Wexp,
                                                 float* __restrict__ outbuf,
                                                 unsigned* __restrict__ counters) {
    const int DB = blockIdx.x >> 4, KS = blockIdx.x & 15;
    char* dst = (char*)(outbuf + AST_F) + (size_t)blockIdx.x * 32768;
    for (int it = 0; it < 8; ++it) {
        int slot = threadIdx.x + it * 256;      // 0..2047
        int r = slot >> 4, P = slot & 15;
        int L = P ^ (r & 15);
        int part = L >> 3, oct = L & 7;
        const float* src = Wexp + (size_t)(DB * 128 + r) * CIN + KS * 64 + oct * 8;
        unsigned short v[8] __attribute__((aligned(16)));
#pragma unroll
        for (int j = 0; j < 8; ++j) {
            float xv = src[j];
            unsigned short hi = f2bf(xv);
            v[j] = part ? f2bf(xv - bf2f(hi)) : hi;
        }
        *(bf16x8*)(dst + r * 256 + P * 16) = *(const bf16x8*)v;
    }
    if (blockIdx.x == 0 && threadIdx.x < 32) counters[threadIdx.x] = 0u;
}

// ---------------- GEMM: bf16x3 MFMA, fused in-kernel B conversion ---------------
// 128x128 tile, 4 waves x 64x64, BK=64. A from staged swizzled image via
// global_load_lds; B converted fp32->hi/lo bf16 in registers, ds_write_b128
// into the same swizzled layout. Fragment-read/MFMA code identical to R2/R3.
__global__ __launch_bounds__(256) void gemm_fused(const float* __restrict__ x,
                                                  const float* __restrict__ stagedA,
                                                  const float* __restrict__ bexp,
                                                  float* __restrict__ cand_val,
                                                  unsigned* __restrict__ cand_idx,
                                                  unsigned* __restrict__ counters,
                                                  int cap) {
    __shared__ char lds[65536];
    __shared__ float s_cv[512];
    __shared__ unsigned s_ci[512];
    __shared__ unsigned s_cnt, s_base;

    const int tid = threadIdx.x;
    const int l = tid & 63, w = tid >> 6;
    const int wm = w >> 1, wn = w & 1;
    const int bx = blockIdx.x, by = blockIdx.y, b = blockIdx.z;

    const char* Achunk0 = (const char*)stagedA + (size_t)(by * 16) * 32768;
    const float* xb = x + (size_t)b * CIN * TT + bx * 128;   // column-block base

    f32x4 acc[4][4];
#pragma unroll
    for (int i = 0; i < 4; ++i)
#pragma unroll
        for (int j = 0; j < 4; ++j) acc[i][j] = (f32x4)0.f;

    char* ldsA = &lds[0];
    char* ldsB = &lds[32768];
    for (int ks = 0; ks < 16; ++ks) {
        const int k0 = ks * 64;
        // A staging: async global->LDS, 8 KB per wave (issue first, runs async)
        {
            const char* gsrcA = Achunk0 + (size_t)ks * 32768 + w * 8192;
            char* ldstA = ldsA + w * 8192;
#pragma unroll
            for (int n = 0; n < 8; ++n)
                gload16(gsrcA + n * 1024 + l * 16, (void*)(ldstA + n * 1024));
        }
        // B staging: read x fp32 (k-strided, wave-coalesced in t), convert to
        // hi/lo bf16, write swizzled 16B slots. 4 tasks/thread = (t, octet L).
#pragma unroll
        for (int q = 0; q < 4; ++q) {
            int task = tid + q * 256;            // 0..1023
            int t = task & 127, L = task >> 7;   // L in 0..7
            const float* src = xb + (size_t)(k0 + L * 8) * TT + t;
            float v[8];
#pragma unroll
            for (int j = 0; j < 8; ++j) v[j] = src[(size_t)j * TT];
            unsigned short hi[8] __attribute__((aligned(16)));
            unsigned short lo[8] __attribute__((aligned(16)));
#pragma unroll
            for (int j = 0; j < 8; ++j) {
                hi[j] = f2bf(v[j]);
                lo[j] = f2bf(v[j] - bf2f(hi[j]));
            }
            int Ph = L ^ (t & 15), Pl = (L + 8) ^ (t & 15);
            *(bf16x8*)(ldsB + t * 256 + Ph * 16) = *(const bf16x8*)hi;
            *(bf16x8*)(ldsB + t * 256 + Pl * 16) = *(const bf16x8*)lo;
        }
        asm volatile("s_waitcnt vmcnt(0)" ::: "memory");
        __syncthreads();

#pragma unroll
        for (int s = 0; s < 2; ++s) {
            bf16x8 af[4][2], bfr[4][2];
#pragma unroll
            for (int i = 0; i < 4; ++i) {
                int r = wm * 64 + i * 16 + (l & 15);
#pragma unroll
                for (int p = 0; p < 2; ++p) {
                    int L = p * 8 + s * 4 + (l >> 4);
                    int P = L ^ (r & 15);
                    af[i][p] = *(const bf16x8*)(ldsA + r * 256 + P * 16);
                }
            }
#pragma unroll
            for (int j = 0; j < 4; ++j) {
                int r = wn * 64 + j * 16 + (l & 15);
#pragma unroll
                for (int p = 0; p < 2; ++p) {
                    int L = p * 8 + s * 4 + (l >> 4);
                    int P = L ^ (r & 15);
                    bfr[j][p] = *(const bf16x8*)(ldsB + r * 256 + P * 16);
                }
            }
#pragma unroll
            for (int i = 0; i < 4; ++i)
#pragma unroll
                for (int j = 0; j < 4; ++j) {
                    acc[i][j] = __builtin_amdgcn_mfma_f32_16x16x32_bf16(af[i][0], bfr[j][0], acc[i][j], 0, 0, 0);
                    acc[i][j] = __builtin_amdgcn_mfma_f32_16x16x32_bf16(af[i][1], bfr[j][0], acc[i][j], 0, 0, 0);
                    acc[i][j] = __builtin_amdgcn_mfma_f32_16x16x32_bf16(af[i][0], bfr[j][1], acc[i][j], 0, 0, 0);
                }
        }
        __syncthreads();
    }

    // Epilogue: bias + threshold candidate collection.
    if (tid == 0) s_cnt = 0;
    __syncthreads();
#pragma unroll
    for (int i = 0; i < 4; ++i)
#pragma unroll
        for (int j = 0; j < 4; ++j)
#pragma unroll
            for (int q = 0; q < 4; ++q) {
                int d = by * 128 + wm * 64 + i * 16 + (l >> 4) * 4 + q;
                int t = bx * 128 + wn * 64 + j * 16 + (l & 15);
                float val = acc[i][j][q] + bexp[d];
                if (val > THRESH) {
                    unsigned p = atomicAdd(&s_cnt, 1u);
                    if (p < 512u) {
                        s_cv[p] = val;
                        s_ci[p] = (unsigned)(d * TT + t);
                    }
                }
            }
    __syncthreads();
    unsigned n = s_cnt < 512u ? s_cnt : 512u;
    if (tid == 0) s_base = atomicAdd(&counters[b], n);
    __syncthreads();
    unsigned base = s_base;
    for (unsigned i = tid; i < n; i += 256u) {
        unsigned pos = base + i;
        if (pos < (unsigned)cap) {
            cand_val[(size_t)b * cap + pos] = s_cv[i];
            cand_idx[(size_t)b * cap + pos] = s_ci[i];
        }
    }
}

// ---------------- zero the sparse output region (268 MB) ------------------------
__global__ __launch_bounds__(256) void zero_sparse(float* __restrict__ out) {
    const size_t N4 = (size_t)B_SZ * SPARSE_PER_B / 4;
    float4* o4 = (float4*)(out + (size_t)OUT_ELEMS);
    const float4 z = make_float4(0.f, 0.f, 0.f, 0.f);
    for (size_t i = blockIdx.x * blockDim.x + threadIdx.x; i < N4;
         i += (size_t)gridDim.x * blockDim.x)
        o4[i] = z;
}

// ---------------- merged selection: kth radix + classify + exact border + emit --
__global__ __launch_bounds__(256) void select_all(const float* __restrict__ cand_val,
                                                  const unsigned* __restrict__ cand_idx,
                                                  const unsigned* __restrict__ counters,
                                                  float* __restrict__ sel_val,
                                                  unsigned* __restrict__ sel_idx,
                                                  const float* __restrict__ x,
                                                  const float* __restrict__ Wexp,
                                                  const float* __restrict__ bexp,
                                                  float* __restrict__ d_out,
                                                  int cap) {
    const int b = blockIdx.x;
    const int tid = threadIdx.x;
    const float* cv = cand_val + (size_t)b * cap;
    const unsigned* ci = cand_idx + (size_t)b * cap;
    unsigned nc = counters[b];
    int n = (int)(nc < (unsigned)cap ? nc : (unsigned)cap);

    __shared__ unsigned hist[256];
    __shared__ float red[256];
    __shared__ unsigned s_sel, s_rem, s_scnt, s_bcnt;
    __shared__ float s_bv[BORDER_CAP];
    __shared__ unsigned s_bi[BORDER_CAP];

    for (int i = tid; i < KEEP; i += 256) {
        sel_val[b * KEEP + i] = 0.f;
        sel_idx[b * KEEP + i] = 0u;
    }

    // 4-pass radix: exact 32 bits of the approx rank-512 value (all vals > 3 > 0)
    unsigned prefix = 0;
    int remaining = KEEP;
    for (int pass = 0; pass < 4; ++pass) {
        int shift = 24 - pass * 8;
        hist[tid] = 0;
        __syncthreads();
        for (int i = tid; i < n; i += 256) {
            unsigned u = __float_as_uint(cv[i]);
            unsigned hb = (pass == 0) ? 0u : (u >> (shift + 8));
            if (hb == prefix) atomicAdd(&hist[(u >> shift) & 255u], 1u);
        }
        __syncthreads();
        if (tid == 0) {
            int rem = remaining;
            unsigned selb = 0;
            for (int byte = 255; byte >= 0; --byte) {
                int c = (int)hist[byte];
                if (c >= rem) { selb = (unsigned)byte; break; }
                rem -= c;
            }
            s_sel = selb;
            s_rem = (unsigned)rem;
        }
        __syncthreads();
        prefix = (prefix << 8) | s_sel;
        remaining = (int)s_rem;
        __syncthreads();
    }

    // classify: sure-in emit directly; borderline collect
    if (tid == 0) { s_scnt = 0; s_bcnt = 0; }
    __syncthreads();
    const float kth = __uint_as_float(prefix);
    const float hiv = kth + EPS_SEL, lov = kth - EPS_SEL;
    float* sparse = d_out + (size_t)OUT_ELEMS + (size_t)b * SPARSE_PER_B;
    for (int i = tid; i < n; i += 256) {
        float v = cv[i];
        if (v > hiv) {
            unsigned p = atomicAdd(&s_scnt, 1u);
            unsigned idx = ci[i];
            sel_val[b * KEEP + p] = v;
            sel_idx[b * KEEP + p] = idx;
            sparse[idx] = v;
        } else if (v >= lov) {
            unsigned q = atomicAdd(&s_bcnt, 1u);
            if (q < BORDER_CAP) s_bi[q] = (unsigned)i;
        }
    }
    __syncthreads();
    int nsure = (int)s_scnt;
    int nb = (int)(s_bcnt < BORDER_CAP ? s_bcnt : BORDER_CAP);

    // exact fp32 recompute of borderline candidates (typically 0-2)
    const float* xb = x + (size_t)b * CIN * TT;
    for (int j = 0; j < nb; ++j) {
        unsigned idx = ci[s_bi[j]];
        int d = (int)(idx >> 13), t = (int)(idx & 8191u);
        const float* wr = Wexp + (size_t)d * CIN;
        float ssum = 0.f;
        for (int k = tid; k < CIN; k += 256)
            ssum += xb[(size_t)k * TT + t] * wr[k];
        red[tid] = ssum;
        __syncthreads();
        for (int off = 128; off > 0; off >>= 1) {
            if (tid < off) red[tid] += red[tid + off];
            __syncthreads();
        }
        if (tid == 0) s_bv[j] = red[0] + bexp[d];
        __syncthreads();
    }

    // rank borderline exactly, fill remaining slots
    int r = KEEP - nsure;
    if (r > nb) r = nb;
    if (r < 0) r = 0;
    if (tid < nb) {
        float v = s_bv[tid];
        unsigned idx = ci[s_bi[tid]];
        int rank = 0;
        for (int j = 0; j < nb; ++j) {
            float vj = s_bv[j];
            unsigned ij = ci[s_bi[j]];
            if (vj > v || (vj == v && ij < idx)) rank++;
        }
        if (rank < r) {
            int p = nsure + rank;
            sel_val[b * KEEP + p] = v;
            sel_idx[b * KEEP + p] = idx;
            sparse[idx] = v;
        }
    }
}

// ---------------- fused dense fill + sparse second GEMM -------------------------
// out[b,c,t] = bcon[c] + sum_{j: t_j==t} v_j * Wcon[c][d_j]; pure coalesced write.
__global__ __launch_bounds__(256) void fill_dense(const float* __restrict__ bcon,
                                                  const float* __restrict__ Wcon,
                                                  const float* __restrict__ sel_val,
                                                  const unsigned* __restrict__ sel_idx,
                                                  float* __restrict__ out) {
    const int tcb = blockIdx.x;          // 128 chunks of 64 t
    const int cb  = blockIdx.y;          // 4 chunks of 256 c
    const int b   = blockIdx.z;
    const int tid = threadIdx.x;
    const int t0 = tcb * 64, c0 = cb * 256;

    __shared__ float s_v[BORDER_CAP];
    __shared__ int s_t[BORDER_CAP], s_d[BORDER_CAP];
    __shared__ unsigned s_ne;
    if (tid == 0) s_ne = 0;
    __syncthreads();
    for (int i = tid; i < KEEP; i += 256) {
        float v = sel_val[b * KEEP + i];
        if (v != 0.f) {
            unsigned idx = sel_idx[b * KEEP + i];
            int t = (int)(idx & 8191u);
            if (t >= t0 && t < t0 + 64) {
                unsigned p = atomicAdd(&s_ne, 1u);
                if (p < BORDER_CAP) {
                    s_v[p] = v;
                    s_t[p] = t - t0;
                    s_d[p] = (int)(idx >> 13);
                }
            }
        }
    }
    __syncthreads();
    const int ne = (int)(s_ne < BORDER_CAP ? s_ne : BORDER_CAP);
    const int lane16 = tid & 15;         // t-quad within chunk
    const int cr = tid >> 4;             // 16 c-rows in flight

    for (int it = 0; it < 16; ++it) {
        int c = c0 + it * 16 + cr;
        float bias = bcon[c];
        float v0 = bias, v1 = bias, v2 = bias, v3 = bias;
        for (int j = 0; j < ne; ++j) {
            int tj = s_t[j];
            if ((tj >> 2) == lane16) {
                float add = s_v[j] * Wcon[(size_t)c * DHI + s_d[j]];
                int q = tj & 3;
                if (q == 0) v0 += add;
                else if (q == 1) v1 += add;
                else if (q == 2) v2 += add;
                else v3 += add;
            }
        }
        *(float4*)(&out[(((size_t)(b * CIN + c)) << 13) + t0 + lane16 * 4]) =
            make_float4(v0, v1, v2, v3);
    }
}

extern "C" void kernel_launch(void* const* d_in, const int* in_sizes, int n_in,
                              void* d_out, int out_size, void* d_ws, size_t ws_size,
                              hipStream_t stream) {
    const float* x    = (const float*)d_in[0];
    const float* Wexp = (const float*)d_in[1];
    const float* bexp = (const float*)d_in[2];
    const float* Wcon = (const float*)d_in[3];
    const float* bcon = (const float*)d_in[4];
    float* out = (float*)d_out;

    unsigned* counters = (unsigned*)((char*)d_ws + WS_COUNTERS);
    float*    sel_val  = (float*)((char*)d_ws + WS_SELV);
    unsigned* sel_idx  = (unsigned*)((char*)d_ws + WS_SELI);
    char* cand_base = (char*)d_ws + WS_CAND;
    size_t remain = ws_size - WS_CAND;
    size_t cap_sz = remain / ((size_t)B_SZ * 8);
    int cap = (int)(cap_sz < (size_t)65536 ? cap_sz : (size_t)65536);
    float*    cand_val = (float*)cand_base;
    unsigned* cand_idx = (unsigned*)(cand_base + (size_t)B_SZ * cap * 4);

    // 1) stage split-precision A into d_out's sparse region (8 MB, reused 64x)
    convert_A<<<256, 256, 0, stream>>>(Wexp, out, counters);

    // 2) MFMA bf16x3 GEMM with fused in-kernel B conversion + candidate collect
    gemm_fused<<<dim3(64, 16, 4), 256, 0, stream>>>(x, out + AST_F, bexp,
                                                    cand_val, cand_idx, counters, cap);

    // 3) zero sparse output region (A staging dead now)
    zero_sparse<<<2048, 256, 0, stream>>>(out);

    // 4) merged selection: approx kth -> sure emit -> exact borderline -> finalize
    select_all<<<B_SZ, 256, 0, stream>>>(cand_val, cand_idx, counters, sel_val,
                                         sel_idx, x, Wexp, bexp, out, cap);

    // 5) fused dense bias fill + sparse second GEMM (no atomics)
    fill_dense<<<dim3(128, 4, B_SZ), 256, 0, stream>>>(bcon, Wcon, sel_val, sel_idx, out);
}

// Round 6
// 708.243 us; speedup vs baseline: 2.5045x; 1.0348x over previous
//
#include <hip/hip_runtime.h>

#define B_SZ 4
#define CIN 1024
#define DHI 2048
#define TT 8192
#define KEEP 512
#define OUT_ELEMS (B_SZ*CIN*TT)            // 33554432
#define SPARSE_PER_B (DHI*TT)              // 16777216
#define THRESH 3.0f
#define EPS_SEL 5e-4f
#define BORDER_CAP 64

// A staged bf16 hi/lo image lives in the (not-yet-written) sparse region of
// d_out, overwritten later by zero_sparse. Offset in floats.
#define AST_F ((size_t)OUT_ELEMS)                  // A staged: 8 MB

typedef short bf16x8 __attribute__((ext_vector_type(8)));
typedef float f32x4 __attribute__((ext_vector_type(4)));

__device__ __forceinline__ unsigned short f2bf(float x) {
    unsigned u = __float_as_uint(x);
    return (unsigned short)((u + 0x7fffu + ((u >> 16) & 1u)) >> 16);
}
__device__ __forceinline__ float bf2f(unsigned short h) {
    return __uint_as_float(((unsigned)h) << 16);
}
__device__ __forceinline__ void gload16(const void* g, void* l) {
    __builtin_amdgcn_global_load_lds((const __attribute__((address_space(1))) void*)g,
                                     (__attribute__((address_space(3))) void*)l, 16, 0, 0);
}

// ws layout: counters[0..31] | sel_val[B*512] | sel_idx[B*512] | cand arrays
#define WS_COUNTERS 0
#define WS_SELV 256
#define WS_SELI (256 + 8192)
#define WS_CAND (256 + 16384)

// ---------------- convert A: W_exp [2048][1024] fp32 -> swizzled hi/lo tiles ---
// chunk (DB,KS): 128 rows(d) x 256B: [hi 64k | lo 64k], 16B slot P holds logical
// slot L = P ^ (r&15); L<8: hi octet L; L>=8: lo octet L-8.  (RNE split: A is
// converted once, cold — keep max accuracy here.)
__global__ __launch_bounds__(256) void convert_A(const float* __restrict__ Wexp,
                                                 float* __restrict__ outbuf,
                                                 unsigned* __restrict__ counters) {
    const int DB = blockIdx.x >> 4, KS = blockIdx.x & 15;
    char* dst = (char*)(outbuf + AST_F) + (size_t)blockIdx.x * 32768;
    for (int it = 0; it < 8; ++it) {
        int slot = threadIdx.x + it * 256;      // 0..2047
        int r = slot >> 4, P = slot & 15;
        int L = P ^ (r & 15);
        int part = L >> 3, oct = L & 7;
        const float* src = Wexp + (size_t)(DB * 128 + r) * CIN + KS * 64 + oct * 8;
        unsigned short v[8] __attribute__((aligned(16)));
#pragma unroll
        for (int j = 0; j < 8; ++j) {
            float xv = src[j];
            unsigned short hi = f2bf(xv);
            v[j] = part ? f2bf(xv - bf2f(hi)) : hi;
        }
        *(bf16x8*)(dst + r * 256 + P * 16) = *(const bf16x8*)v;
    }
    if (blockIdx.x == 0 && threadIdx.x < 32) counters[threadIdx.x] = 0u;
}

// ---------------- GEMM: bf16x3 MFMA, fused in-kernel B conversion ---------------
// 128x128 tile, 4 waves x 64x64, BK=64. A from staged swizzled image via
// global_load_lds; B converted fp32 -> hi/lo bf16 via TRUNCATION split (4 VALU
// ops/elem: shr, and, sub, shr) and ds_write_b128 into the swizzled layout.
// Residual 2^-16 rel (vs 2^-17 RNE) — absorbed by EPS_SEL exact recheck.
__global__ __launch_bounds__(256) void gemm_fused(const float* __restrict__ x,
                                                  const float* __restrict__ stagedA,
                                                  const float* __restrict__ bexp,
                                                  float* __restrict__ cand_val,
                                                  unsigned* __restrict__ cand_idx,
                                                  unsigned* __restrict__ counters,
                                                  int cap) {
    __shared__ char lds[65536];
    __shared__ float s_cv[512];
    __shared__ unsigned s_ci[512];
    __shared__ unsigned s_cnt, s_base;

    const int tid = threadIdx.x;
    const int l = tid & 63, w = tid >> 6;
    const int wm = w >> 1, wn = w & 1;
    const int bx = blockIdx.x, by = blockIdx.y, b = blockIdx.z;

    const char* Achunk0 = (const char*)stagedA + (size_t)(by * 16) * 32768;
    const float* xb = x + (size_t)b * CIN * TT + bx * 128;   // column-block base

    f32x4 acc[4][4];
#pragma unroll
    for (int i = 0; i < 4; ++i)
#pragma unroll
        for (int j = 0; j < 4; ++j) acc[i][j] = (f32x4)0.f;

    char* ldsA = &lds[0];
    char* ldsB = &lds[32768];
    for (int ks = 0; ks < 16; ++ks) {
        const int k0 = ks * 64;
        // A staging: async global->LDS, 8 KB per wave (issue first, runs async)
        {
            const char* gsrcA = Achunk0 + (size_t)ks * 32768 + w * 8192;
            char* ldstA = ldsA + w * 8192;
#pragma unroll
            for (int n = 0; n < 8; ++n)
                gload16(gsrcA + n * 1024 + l * 16, (void*)(ldstA + n * 1024));
        }
        // B staging: read x fp32 (k-strided, wave-coalesced in t), truncation
        // split to hi/lo bf16, write swizzled 16B slots.
#pragma unroll
        for (int q = 0; q < 4; ++q) {
            int task = tid + q * 256;            // 0..1023
            int t = task & 127, L = task >> 7;   // L in 0..7
            const float* src = xb + (size_t)(k0 + L * 8) * TT + t;
            float v[8];
#pragma unroll
            for (int j = 0; j < 8; ++j) v[j] = src[(size_t)j * TT];
            unsigned short hi[8] __attribute__((aligned(16)));
            unsigned short lo[8] __attribute__((aligned(16)));
#pragma unroll
            for (int j = 0; j < 8; ++j) {
                unsigned u = __float_as_uint(v[j]);
                hi[j] = (unsigned short)(u >> 16);
                float rem = v[j] - __uint_as_float(u & 0xFFFF0000u);
                lo[j] = (unsigned short)(__float_as_uint(rem) >> 16);
            }
            int Ph = L ^ (t & 15), Pl = (L + 8) ^ (t & 15);
            *(bf16x8*)(ldsB + t * 256 + Ph * 16) = *(const bf16x8*)hi;
            *(bf16x8*)(ldsB + t * 256 + Pl * 16) = *(const bf16x8*)lo;
        }
        asm volatile("s_waitcnt vmcnt(0)" ::: "memory");
        __syncthreads();

#pragma unroll
        for (int s = 0; s < 2; ++s) {
            bf16x8 af[4][2], bfr[4][2];
#pragma unroll
            for (int i = 0; i < 4; ++i) {
                int r = wm * 64 + i * 16 + (l & 15);
#pragma unroll
                for (int p = 0; p < 2; ++p) {
                    int L = p * 8 + s * 4 + (l >> 4);
                    int P = L ^ (r & 15);
                    af[i][p] = *(const bf16x8*)(ldsA + r * 256 + P * 16);
                }
            }
#pragma unroll
            for (int j = 0; j < 4; ++j) {
                int r = wn * 64 + j * 16 + (l & 15);
#pragma unroll
                for (int p = 0; p < 2; ++p) {
                    int L = p * 8 + s * 4 + (l >> 4);
                    int P = L ^ (r & 15);
                    bfr[j][p] = *(const bf16x8*)(ldsB + r * 256 + P * 16);
                }
            }
#pragma unroll
            for (int i = 0; i < 4; ++i)
#pragma unroll
                for (int j = 0; j < 4; ++j) {
                    acc[i][j] = __builtin_amdgcn_mfma_f32_16x16x32_bf16(af[i][0], bfr[j][0], acc[i][j], 0, 0, 0);
                    acc[i][j] = __builtin_amdgcn_mfma_f32_16x16x32_bf16(af[i][1], bfr[j][0], acc[i][j], 0, 0, 0);
                    acc[i][j] = __builtin_amdgcn_mfma_f32_16x16x32_bf16(af[i][0], bfr[j][1], acc[i][j], 0, 0, 0);
                }
        }
        __syncthreads();
    }

    // Epilogue: bias + threshold candidate collection.
    if (tid == 0) s_cnt = 0;
    __syncthreads();
#pragma unroll
    for (int i = 0; i < 4; ++i)
#pragma unroll
        for (int j = 0; j < 4; ++j)
#pragma unroll
            for (int q = 0; q < 4; ++q) {
                int d = by * 128 + wm * 64 + i * 16 + (l >> 4) * 4 + q;
                int t = bx * 128 + wn * 64 + j * 16 + (l & 15);
                float val = acc[i][j][q] + bexp[d];
                if (val > THRESH) {
                    unsigned p = atomicAdd(&s_cnt, 1u);
                    if (p < 512u) {
                        s_cv[p] = val;
                        s_ci[p] = (unsigned)(d * TT + t);
                    }
                }
            }
    __syncthreads();
    unsigned n = s_cnt < 512u ? s_cnt : 512u;
    if (tid == 0) s_base = atomicAdd(&counters[b], n);
    __syncthreads();
    unsigned base = s_base;
    for (unsigned i = tid; i < n; i += 256u) {
        unsigned pos = base + i;
        if (pos < (unsigned)cap) {
            cand_val[(size_t)b * cap + pos] = s_cv[i];
            cand_idx[(size_t)b * cap + pos] = s_ci[i];
        }
    }
}

// ---------------- zero the sparse output region (268 MB) ------------------------
__global__ __launch_bounds__(256) void zero_sparse(float* __restrict__ out) {
    const size_t N4 = (size_t)B_SZ * SPARSE_PER_B / 4;
    float4* o4 = (float4*)(out + (size_t)OUT_ELEMS);
    const float4 z = make_float4(0.f, 0.f, 0.f, 0.f);
    for (size_t i = blockIdx.x * blockDim.x + threadIdx.x; i < N4;
         i += (size_t)gridDim.x * blockDim.x)
        o4[i] = z;
}

// ---------------- merged selection: kth radix + classify + exact border + emit --
__global__ __launch_bounds__(256) void select_all(const float* __restrict__ cand_val,
                                                  const unsigned* __restrict__ cand_idx,
                                                  const unsigned* __restrict__ counters,
                                                  float* __restrict__ sel_val,
                                                  unsigned* __restrict__ sel_idx,
                                                  const float* __restrict__ x,
                                                  const float* __restrict__ Wexp,
                                                  const float* __restrict__ bexp,
                                                  float* __restrict__ d_out,
                                                  int cap) {
    const int b = blockIdx.x;
    const int tid = threadIdx.x;
    const float* cv = cand_val + (size_t)b * cap;
    const unsigned* ci = cand_idx + (size_t)b * cap;
    unsigned nc = counters[b];
    int n = (int)(nc < (unsigned)cap ? nc : (unsigned)cap);

    __shared__ unsigned hist[256];
    __shared__ float red[256];
    __shared__ unsigned s_sel, s_rem, s_scnt, s_bcnt;
    __shared__ float s_bv[BORDER_CAP];
    __shared__ unsigned s_bi[BORDER_CAP];

    for (int i = tid; i < KEEP; i += 256) {
        sel_val[b * KEEP + i] = 0.f;
        sel_idx[b * KEEP + i] = 0u;
    }

    // 4-pass radix: exact 32 bits of the approx rank-512 value (all vals > 3 > 0)
    unsigned prefix = 0;
    int remaining = KEEP;
    for (int pass = 0; pass < 4; ++pass) {
        int shift = 24 - pass * 8;
        hist[tid] = 0;
        __syncthreads();
        for (int i = tid; i < n; i += 256) {
            unsigned u = __float_as_uint(cv[i]);
            unsigned hb = (pass == 0) ? 0u : (u >> (shift + 8));
            if (hb == prefix) atomicAdd(&hist[(u >> shift) & 255u], 1u);
        }
        __syncthreads();
        if (tid == 0) {
            int rem = remaining;
            unsigned selb = 0;
            for (int byte = 255; byte >= 0; --byte) {
                int c = (int)hist[byte];
                if (c >= rem) { selb = (unsigned)byte; break; }
                rem -= c;
            }
            s_sel = selb;
            s_rem = (unsigned)rem;
        }
        __syncthreads();
        prefix = (prefix << 8) | s_sel;
        remaining = (int)s_rem;
        __syncthreads();
    }

    // classify: sure-in emit directly; borderline collect
    if (tid == 0) { s_scnt = 0; s_bcnt = 0; }
    __syncthreads();
    const float kth = __uint_as_float(prefix);
    const float hiv = kth + EPS_SEL, lov = kth - EPS_SEL;
    float* sparse = d_out + (size_t)OUT_ELEMS + (size_t)b * SPARSE_PER_B;
    for (int i = tid; i < n; i += 256) {
        float v = cv[i];
        if (v > hiv) {
            unsigned p = atomicAdd(&s_scnt, 1u);
            unsigned idx = ci[i];
            sel_val[b * KEEP + p] = v;
            sel_idx[b * KEEP + p] = idx;
            sparse[idx] = v;
        } else if (v >= lov) {
            unsigned q = atomicAdd(&s_bcnt, 1u);
            if (q < BORDER_CAP) s_bi[q] = (unsigned)i;
        }
    }
    __syncthreads();
    int nsure = (int)s_scnt;
    int nb = (int)(s_bcnt < BORDER_CAP ? s_bcnt : BORDER_CAP);

    // exact fp32 recompute of borderline candidates (typically 0-2)
    const float* xb = x + (size_t)b * CIN * TT;
    for (int j = 0; j < nb; ++j) {
        unsigned idx = ci[s_bi[j]];
        int d = (int)(idx >> 13), t = (int)(idx & 8191u);
        const float* wr = Wexp + (size_t)d * CIN;
        float ssum = 0.f;
        for (int k = tid; k < CIN; k += 256)
            ssum += xb[(size_t)k * TT + t] * wr[k];
        red[tid] = ssum;
        __syncthreads();
        for (int off = 128; off > 0; off >>= 1) {
            if (tid < off) red[tid] += red[tid + off];
            __syncthreads();
        }
        if (tid == 0) s_bv[j] = red[0] + bexp[d];
        __syncthreads();
    }

    // rank borderline exactly, fill remaining slots
    int r = KEEP - nsure;
    if (r > nb) r = nb;
    if (r < 0) r = 0;
    if (tid < nb) {
        float v = s_bv[tid];
        unsigned idx = ci[s_bi[tid]];
        int rank = 0;
        for (int j = 0; j < nb; ++j) {
            float vj = s_bv[j];
            unsigned ij = ci[s_bi[j]];
            if (vj > v || (vj == v && ij < idx)) rank++;
        }
        if (rank < r) {
            int p = nsure + rank;
            sel_val[b * KEEP + p] = v;
            sel_idx[b * KEEP + p] = idx;
            sparse[idx] = v;
        }
    }
}

// ---------------- fused dense fill + sparse second GEMM -------------------------
// out[b,c,t] = bcon[c] + sum_{j: t_j==t} v_j * Wcon[c][d_j]; pure coalesced write.
__global__ __launch_bounds__(256) void fill_dense(const float* __restrict__ bcon,
                                                  const float* __restrict__ Wcon,
                                                  const float* __restrict__ sel_val,
                                                  const unsigned* __restrict__ sel_idx,
                                                  float* __restrict__ out) {
    const int tcb = blockIdx.x;          // 128 chunks of 64 t
    const int cb  = blockIdx.y;          // 4 chunks of 256 c
    const int b   = blockIdx.z;
    const int tid = threadIdx.x;
    const int t0 = tcb * 64, c0 = cb * 256;

    __shared__ float s_v[BORDER_CAP];
    __shared__ int s_t[BORDER_CAP], s_d[BORDER_CAP];
    __shared__ unsigned s_ne;
    if (tid == 0) s_ne = 0;
    __syncthreads();
    for (int i = tid; i < KEEP; i += 256) {
        float v = sel_val[b * KEEP + i];
        if (v != 0.f) {
            unsigned idx = sel_idx[b * KEEP + i];
            int t = (int)(idx & 8191u);
            if (t >= t0 && t < t0 + 64) {
                unsigned p = atomicAdd(&s_ne, 1u);
                if (p < BORDER_CAP) {
                    s_v[p] = v;
                    s_t[p] = t - t0;
                    s_d[p] = (int)(idx >> 13);
                }
            }
        }
    }
    __syncthreads();
    const int ne = (int)(s_ne < BORDER_CAP ? s_ne : BORDER_CAP);
    const int lane16 = tid & 15;         // t-quad within chunk
    const int cr = tid >> 4;             // 16 c-rows in flight

    for (int it = 0; it < 16; ++it) {
        int c = c0 + it * 16 + cr;
        float bias = bcon[c];
        float v0 = bias, v1 = bias, v2 = bias, v3 = bias;
        for (int j = 0; j < ne; ++j) {
            int tj = s_t[j];
            if ((tj >> 2) == lane16) {
                float add = s_v[j] * Wcon[(size_t)c * DHI + s_d[j]];
                int q = tj & 3;
                if (q == 0) v0 += add;
                else if (q == 1) v1 += add;
                else if (q == 2) v2 += add;
                else v3 += add;
            }
        }
        *(float4*)(&out[(((size_t)(b * CIN + c)) << 13) + t0 + lane16 * 4]) =
            make_float4(v0, v1, v2, v3);
    }
}

extern "C" void kernel_launch(void* const* d_in, const int* in_sizes, int n_in,
                              void* d_out, int out_size, void* d_ws, size_t ws_size,
                              hipStream_t stream) {
    const float* x    = (const float*)d_in[0];
    const float* Wexp = (const float*)d_in[1];
    const float* bexp = (const float*)d_in[2];
    const float* Wcon = (const float*)d_in[3];
    const float* bcon = (const float*)d_in[4];
    float* out = (float*)d_out;

    unsigned* counters = (unsigned*)((char*)d_ws + WS_COUNTERS);
    float*    sel_val  = (float*)((char*)d_ws + WS_SELV);
    unsigned* sel_idx  = (unsigned*)((char*)d_ws + WS_SELI);
    char* cand_base = (char*)d_ws + WS_CAND;
    size_t remain = ws_size - WS_CAND;
    size_t cap_sz = remain / ((size_t)B_SZ * 8);
    int cap = (int)(cap_sz < (size_t)65536 ? cap_sz : (size_t)65536);
    float*    cand_val = (float*)cand_base;
    unsigned* cand_idx = (unsigned*)(cand_base + (size_t)B_SZ * cap * 4);

    // 1) stage split-precision A into d_out's sparse region (8 MB, reused 64x)
    convert_A<<<256, 256, 0, stream>>>(Wexp, out, counters);

    // 2) MFMA bf16x3 GEMM with fused in-kernel B conversion + candidate collect
    gemm_fused<<<dim3(64, 16, 4), 256, 0, stream>>>(x, out + AST_F, bexp,
                                                    cand_val, cand_idx, counters, cap);

    // 3) zero sparse output region (A staging dead now)
    zero_sparse<<<2048, 256, 0, stream>>>(out);

    // 4) merged selection: approx kth -> sure emit -> exact borderline -> finalize
    select_all<<<B_SZ, 256, 0, stream>>>(cand_val, cand_idx, counters, sel_val,
                                         sel_idx, x, Wexp, bexp, out, cap);

    // 5) fused dense bias fill + sparse second GEMM (no atomics)
    fill_dense<<<dim3(128, 4, B_SZ), 256, 0, stream>>>(bcon, Wcon, sel_val, sel_idx, out);
}